// Round 2
// baseline (219.792 us; speedup 1.0000x reference)
//
#include <hip/hip_runtime.h>

#define BLOCK 256
#define GRID 2048

typedef float f32x4 __attribute__((ext_vector_type(4)));

__device__ __forceinline__ f32x4 ntload(const f32x4* p) {
  return __builtin_nontemporal_load(p);
}

__device__ __forceinline__ float asym4(f32x4 c, f32x4 t,
                                       float p0, float p1, float p2, float p3) {
  float d0 = c[0] - t[0], d1 = c[1] - t[1], d2 = c[2] - t[2], d3 = c[3] - t[3];
  float e0 = (d0 < 0.0f) ? -p0 * d0 : d0;
  float e1 = (d1 < 0.0f) ? -p1 * d1 : d1;
  float e2 = (d2 < 0.0f) ? -p2 * d2 : d2;
  float e3 = (d3 < 0.0f) ? -p3 * d3 : d3;
  return (e0 + e1) + (e2 + e3);
}

__global__ __launch_bounds__(BLOCK) void asym_l1_partial(
    const f32x4* __restrict__ c4, const f32x4* __restrict__ t4,
    const float* __restrict__ penalty, float* __restrict__ partials, long n4) {
  __shared__ float pen[32];
  if (threadIdx.x < 32) pen[threadIdx.x] = penalty[threadIdx.x];
  __syncthreads();

  const long stride = (long)GRID * BLOCK;
  const long i0 = (long)blockIdx.x * BLOCK + threadIdx.x;

  // col = (4*i) & 31 is invariant across the whole grid-stride walk
  // (4*stride ≡ 0 mod 32), so hoist penalty into 4 registers.
  const int col = (int)((i0 * 4) & 31);
  const float p0 = pen[col], p1 = pen[col + 1], p2 = pen[col + 2], p3 = pen[col + 3];

  float a0 = 0.0f, a1 = 0.0f, a2 = 0.0f, a3 = 0.0f;
  long i = i0;

  // 4x strided unroll: 8 independent nt loads in flight before any use.
  for (; i + 3 * stride < n4; i += 4 * stride) {
    f32x4 c0 = ntload(c4 + i);
    f32x4 c1 = ntload(c4 + i + stride);
    f32x4 c2 = ntload(c4 + i + 2 * stride);
    f32x4 c3 = ntload(c4 + i + 3 * stride);
    f32x4 t0 = ntload(t4 + i);
    f32x4 t1 = ntload(t4 + i + stride);
    f32x4 t2 = ntload(t4 + i + 2 * stride);
    f32x4 t3 = ntload(t4 + i + 3 * stride);
    a0 += asym4(c0, t0, p0, p1, p2, p3);
    a1 += asym4(c1, t1, p0, p1, p2, p3);
    a2 += asym4(c2, t2, p0, p1, p2, p3);
    a3 += asym4(c3, t3, p0, p1, p2, p3);
  }
  for (; i < n4; i += stride) {  // remainder (empty when n4 % (4*stride) == 0)
    a0 += asym4(ntload(c4 + i), ntload(t4 + i), p0, p1, p2, p3);
  }

  float acc = (a0 + a1) + (a2 + a3);

  // wave-64 reduce
  #pragma unroll
  for (int off = 32; off > 0; off >>= 1) acc += __shfl_down(acc, off, 64);

  __shared__ float wsum[BLOCK / 64];
  const int lane = threadIdx.x & 63;
  const int wid  = threadIdx.x >> 6;
  if (lane == 0) wsum[wid] = acc;
  __syncthreads();
  if (threadIdx.x == 0) {
    float s = 0.0f;
    #pragma unroll
    for (int w = 0; w < BLOCK / 64; ++w) s += wsum[w];
    partials[blockIdx.x] = s;
  }
}

__global__ __launch_bounds__(BLOCK) void asym_l1_final(
    const float* __restrict__ partials, float* __restrict__ out,
    int nparts, float inv_n) {
  float acc = 0.0f;
  for (int i = threadIdx.x; i < nparts; i += BLOCK) acc += partials[i];

  #pragma unroll
  for (int off = 32; off > 0; off >>= 1) acc += __shfl_down(acc, off, 64);

  __shared__ float wsum[BLOCK / 64];
  const int lane = threadIdx.x & 63;
  const int wid  = threadIdx.x >> 6;
  if (lane == 0) wsum[wid] = acc;
  __syncthreads();
  if (threadIdx.x == 0) {
    float s = 0.0f;
    #pragma unroll
    for (int w = 0; w < BLOCK / 64; ++w) s += wsum[w];
    out[0] = s * inv_n;
  }
}

extern "C" void kernel_launch(void* const* d_in, const int* in_sizes, int n_in,
                              void* d_out, int out_size, void* d_ws, size_t ws_size,
                              hipStream_t stream) {
  const float* computed = (const float*)d_in[0];
  const float* target   = (const float*)d_in[1];
  const float* penalty  = (const float*)d_in[2];
  float* out = (float*)d_out;
  float* partials = (float*)d_ws;   // GRID * 4 bytes = 8 KB scratch

  const long total = (long)in_sizes[0];              // N * M = 134217728
  const long n4    = total / 4;
  const long n_samples = total / (long)in_sizes[2];  // N (M = in_sizes[2] = 32)
  const float inv_n = 1.0f / (float)n_samples;

  asym_l1_partial<<<GRID, BLOCK, 0, stream>>>(
      (const f32x4*)computed, (const f32x4*)target, penalty, partials, n4);
  asym_l1_final<<<1, BLOCK, 0, stream>>>(partials, out, GRID, inv_n);
}

// Round 3
// 184.048 us; speedup vs baseline: 1.1942x; 1.1942x over previous
//
#include <hip/hip_runtime.h>

#define BLOCK 256
#define GRID 2048
#define UNROLL 4
#define CHUNK (BLOCK * UNROLL)   // float4s per block per iteration (16 KB)

typedef float f32x4 __attribute__((ext_vector_type(4)));

__device__ __forceinline__ float asym4(f32x4 c, f32x4 t,
                                       float p0, float p1, float p2, float p3) {
  float d0 = c[0] - t[0], d1 = c[1] - t[1], d2 = c[2] - t[2], d3 = c[3] - t[3];
  float e0 = (d0 < 0.0f) ? -p0 * d0 : d0;
  float e1 = (d1 < 0.0f) ? -p1 * d1 : d1;
  float e2 = (d2 < 0.0f) ? -p2 * d2 : d2;
  float e3 = (d3 < 0.0f) ? -p3 * d3 : d3;
  return (e0 + e1) + (e2 + e3);
}

__global__ __launch_bounds__(BLOCK) void asym_l1_partial(
    const f32x4* __restrict__ c4, const f32x4* __restrict__ t4,
    const float* __restrict__ penalty, float* __restrict__ partials, long n4) {
  __shared__ float pen[32];
  if (threadIdx.x < 32) pen[threadIdx.x] = penalty[threadIdx.x];
  __syncthreads();

  // col = (4*idx) & 31 with idx = base + u*BLOCK + tid: both base and u*BLOCK
  // are multiples of 8 float4s (32 floats), so col = (4*tid) & 31, invariant.
  const int col = (int)((threadIdx.x * 4) & 31);
  const float p0 = pen[col], p1 = pen[col + 1], p2 = pen[col + 2], p3 = pen[col + 3];

  float a0 = 0.0f, a1 = 0.0f, a2 = 0.0f, a3 = 0.0f;
  const long gstride = (long)GRID * CHUNK;

  long base = (long)blockIdx.x * CHUNK;
  for (; base + CHUNK <= n4; base += gstride) {
    const long i = base + threadIdx.x;
    // 8 independent loads, all within two 16 KB windows (4 KB apart each).
    f32x4 c0 = c4[i];
    f32x4 c1 = c4[i + BLOCK];
    f32x4 c2 = c4[i + 2 * BLOCK];
    f32x4 c3 = c4[i + 3 * BLOCK];
    f32x4 t0 = t4[i];
    f32x4 t1 = t4[i + BLOCK];
    f32x4 t2 = t4[i + 2 * BLOCK];
    f32x4 t3 = t4[i + 3 * BLOCK];
    a0 += asym4(c0, t0, p0, p1, p2, p3);
    a1 += asym4(c1, t1, p0, p1, p2, p3);
    a2 += asym4(c2, t2, p0, p1, p2, p3);
    a3 += asym4(c3, t3, p0, p1, p2, p3);
  }
  // remainder (never taken for N*M = 2^27, kept for safety)
  for (long i = base + threadIdx.x; i < n4; i += BLOCK) {
    a0 += asym4(c4[i], t4[i], p0, p1, p2, p3);
  }

  float acc = (a0 + a1) + (a2 + a3);

  #pragma unroll
  for (int off = 32; off > 0; off >>= 1) acc += __shfl_down(acc, off, 64);

  __shared__ float wsum[BLOCK / 64];
  const int lane = threadIdx.x & 63;
  const int wid  = threadIdx.x >> 6;
  if (lane == 0) wsum[wid] = acc;
  __syncthreads();
  if (threadIdx.x == 0) {
    float s = 0.0f;
    #pragma unroll
    for (int w = 0; w < BLOCK / 64; ++w) s += wsum[w];
    partials[blockIdx.x] = s;
  }
}

__global__ __launch_bounds__(BLOCK) void asym_l1_final(
    const float* __restrict__ partials, float* __restrict__ out,
    int nparts, float inv_n) {
  float acc = 0.0f;
  for (int i = threadIdx.x; i < nparts; i += BLOCK) acc += partials[i];

  #pragma unroll
  for (int off = 32; off > 0; off >>= 1) acc += __shfl_down(acc, off, 64);

  __shared__ float wsum[BLOCK / 64];
  const int lane = threadIdx.x & 63;
  const int wid  = threadIdx.x >> 6;
  if (lane == 0) wsum[wid] = acc;
  __syncthreads();
  if (threadIdx.x == 0) {
    float s = 0.0f;
    #pragma unroll
    for (int w = 0; w < BLOCK / 64; ++w) s += wsum[w];
    out[0] = s * inv_n;
  }
}

extern "C" void kernel_launch(void* const* d_in, const int* in_sizes, int n_in,
                              void* d_out, int out_size, void* d_ws, size_t ws_size,
                              hipStream_t stream) {
  const float* computed = (const float*)d_in[0];
  const float* target   = (const float*)d_in[1];
  const float* penalty  = (const float*)d_in[2];
  float* out = (float*)d_out;
  float* partials = (float*)d_ws;   // GRID * 4 bytes = 8 KB scratch

  const long total = (long)in_sizes[0];              // N * M = 134217728
  const long n4    = total / 4;
  const long n_samples = total / (long)in_sizes[2];  // N (M = in_sizes[2] = 32)
  const float inv_n = 1.0f / (float)n_samples;

  asym_l1_partial<<<GRID, BLOCK, 0, stream>>>(
      (const f32x4*)computed, (const f32x4*)target, penalty, partials, n4);
  asym_l1_final<<<1, BLOCK, 0, stream>>>(partials, out, GRID, inv_n);
}

// Round 4
// 161.217 us; speedup vs baseline: 1.3633x; 1.1416x over previous
//
#include <hip/hip_runtime.h>

#define BLOCK 256
#define GRID 2048
#define UNROLL 4
#define CHUNK (BLOCK * UNROLL)   // float4s per block per iteration (16 KB)

typedef float f32x4 __attribute__((ext_vector_type(4)));

__device__ __forceinline__ f32x4 ntload(const f32x4* p) {
  return __builtin_nontemporal_load(p);
}

__device__ __forceinline__ float asym4(f32x4 c, f32x4 t,
                                       float p0, float p1, float p2, float p3) {
  float d0 = c[0] - t[0], d1 = c[1] - t[1], d2 = c[2] - t[2], d3 = c[3] - t[3];
  float e0 = (d0 < 0.0f) ? -p0 * d0 : d0;
  float e1 = (d1 < 0.0f) ? -p1 * d1 : d1;
  float e2 = (d2 < 0.0f) ? -p2 * d2 : d2;
  float e3 = (d3 < 0.0f) ? -p3 * d3 : d3;
  return (e0 + e1) + (e2 + e3);
}

__global__ __launch_bounds__(BLOCK) void asym_l1_partial(
    const f32x4* __restrict__ c4, const f32x4* __restrict__ t4,
    const float* __restrict__ penalty, float* __restrict__ partials, long n4) {
  __shared__ float pen[32];
  if (threadIdx.x < 32) pen[threadIdx.x] = penalty[threadIdx.x];
  __syncthreads();

  // col = (4*idx) & 31 with idx = base + u*BLOCK + tid: both base and u*BLOCK
  // are multiples of 8 float4s (32 floats), so col = (4*tid) & 31, invariant.
  const int col = (int)((threadIdx.x * 4) & 31);
  const float p0 = pen[col], p1 = pen[col + 1], p2 = pen[col + 2], p3 = pen[col + 3];

  float a0 = 0.0f, a1 = 0.0f, a2 = 0.0f, a3 = 0.0f;
  const long gstride = (long)GRID * CHUNK;

  long base = (long)blockIdx.x * CHUNK;
  for (; base + CHUNK <= n4; base += gstride) {
    const long i = base + threadIdx.x;
    // 8 independent nontemporal loads, two 16 KB windows (4 KB apart each).
    f32x4 c0 = ntload(c4 + i);
    f32x4 c1 = ntload(c4 + i + BLOCK);
    f32x4 c2 = ntload(c4 + i + 2 * BLOCK);
    f32x4 c3 = ntload(c4 + i + 3 * BLOCK);
    f32x4 t0 = ntload(t4 + i);
    f32x4 t1 = ntload(t4 + i + BLOCK);
    f32x4 t2 = ntload(t4 + i + 2 * BLOCK);
    f32x4 t3 = ntload(t4 + i + 3 * BLOCK);
    a0 += asym4(c0, t0, p0, p1, p2, p3);
    a1 += asym4(c1, t1, p0, p1, p2, p3);
    a2 += asym4(c2, t2, p0, p1, p2, p3);
    a3 += asym4(c3, t3, p0, p1, p2, p3);
  }
  // remainder (never taken for N*M = 2^27, kept for safety)
  for (long i = base + threadIdx.x; i < n4; i += BLOCK) {
    a0 += asym4(c4[i], t4[i], p0, p1, p2, p3);
  }

  float acc = (a0 + a1) + (a2 + a3);

  #pragma unroll
  for (int off = 32; off > 0; off >>= 1) acc += __shfl_down(acc, off, 64);

  __shared__ float wsum[BLOCK / 64];
  const int lane = threadIdx.x & 63;
  const int wid  = threadIdx.x >> 6;
  if (lane == 0) wsum[wid] = acc;
  __syncthreads();
  if (threadIdx.x == 0) {
    float s = 0.0f;
    #pragma unroll
    for (int w = 0; w < BLOCK / 64; ++w) s += wsum[w];
    partials[blockIdx.x] = s;
  }
}

__global__ __launch_bounds__(BLOCK) void asym_l1_final(
    const float* __restrict__ partials, float* __restrict__ out,
    int nparts, float inv_n) {
  float acc = 0.0f;
  for (int i = threadIdx.x; i < nparts; i += BLOCK) acc += partials[i];

  #pragma unroll
  for (int off = 32; off > 0; off >>= 1) acc += __shfl_down(acc, off, 64);

  __shared__ float wsum[BLOCK / 64];
  const int lane = threadIdx.x & 63;
  const int wid  = threadIdx.x >> 6;
  if (lane == 0) wsum[wid] = acc;
  __syncthreads();
  if (threadIdx.x == 0) {
    float s = 0.0f;
    #pragma unroll
    for (int w = 0; w < BLOCK / 64; ++w) s += wsum[w];
    out[0] = s * inv_n;
  }
}

extern "C" void kernel_launch(void* const* d_in, const int* in_sizes, int n_in,
                              void* d_out, int out_size, void* d_ws, size_t ws_size,
                              hipStream_t stream) {
  const float* computed = (const float*)d_in[0];
  const float* target   = (const float*)d_in[1];
  const float* penalty  = (const float*)d_in[2];
  float* out = (float*)d_out;
  float* partials = (float*)d_ws;   // GRID * 4 bytes = 8 KB scratch

  const long total = (long)in_sizes[0];              // N * M = 134217728
  const long n4    = total / 4;
  const long n_samples = total / (long)in_sizes[2];  // N (M = in_sizes[2] = 32)
  const float inv_n = 1.0f / (float)n_samples;

  asym_l1_partial<<<GRID, BLOCK, 0, stream>>>(
      (const f32x4*)computed, (const f32x4*)target, penalty, partials, n4);
  asym_l1_final<<<1, BLOCK, 0, stream>>>(partials, out, GRID, inv_n);
}